// Round 4
// baseline (4424.753 us; speedup 1.0000x reference)
//
#include <hip/hip_runtime.h>
#include <hip/hip_bf16.h>
#include <math.h>

#define T_SEQ   1024
#define BATCH   2
#define EMB     1024
#define NHEAD   16
#define NLAYER  6
#define HDIM    64
#define VOCAB   50257
#define WINDOW  256

typedef short bf16x8 __attribute__((ext_vector_type(8)));
typedef float f32x4  __attribute__((ext_vector_type(4)));

// RNE float -> bf16 bit pattern (inputs are well-behaved; NaN path ignored)
__device__ __forceinline__ unsigned short f2bf(float f) {
    unsigned int u = __float_as_uint(f);
    u += 0x7fffu + ((u >> 16) & 1u);
    return (unsigned short)(u >> 16);
}

// ---------------- wave reduce helpers (wave = 64 lanes) ----------------
__device__ __forceinline__ float waveReduceSum(float v) {
#pragma unroll
    for (int o = 32; o > 0; o >>= 1) v += __shfl_xor(v, o, 64);
    return v;
}
__device__ __forceinline__ float waveReduceMax(float v) {
#pragma unroll
    for (int o = 32; o > 0; o >>= 1) v = fmaxf(v, __shfl_xor(v, o, 64));
    return v;
}

// ---------------- embedding: x = wte[idx] + wpe[t] ----------------
__global__ __launch_bounds__(256) void embed_kernel(
    const int* __restrict__ idx, const float* __restrict__ wte,
    const float* __restrict__ wpe, float* __restrict__ x)
{
    int i  = blockIdx.x * 256 + threadIdx.x;   // over B*T*256 float4 groups
    int e4 = i & 255;
    int bt = i >> 8;                            // 0..B*T-1
    int t  = bt & (T_SEQ - 1);
    int id = idx[bt];
    float4 a = *reinterpret_cast<const float4*>(wte + (size_t)id * EMB + e4 * 4);
    float4 p = *reinterpret_cast<const float4*>(wpe + (size_t)t  * EMB + e4 * 4);
    float4 o; o.x = a.x + p.x; o.y = a.y + p.y; o.z = a.z + p.z; o.w = a.w + p.w;
    *reinterpret_cast<float4*>(x + (size_t)bt * EMB + e4 * 4) = o;
}

// ---------------- LayerNorm of one 1024-row, 256 threads ----------------
__device__ __forceinline__ void ln_row_256(
    const float* __restrict__ in, const float* __restrict__ w,
    const float* __restrict__ bb, float* __restrict__ out)
{
    __shared__ float red[4];
    __shared__ float red2[4];
    int tid = threadIdx.x;
    int wid = tid >> 6, lane = tid & 63;
    float4 v = reinterpret_cast<const float4*>(in)[tid];
    float s = v.x + v.y + v.z + v.w;
    float ws = waveReduceSum(s);
    if (lane == 0) red[wid] = ws;
    __syncthreads();
    float mu = (red[0] + red[1] + red[2] + red[3]) * (1.0f / EMB);
    float dx = v.x - mu, dy = v.y - mu, dz = v.z - mu, dw = v.w - mu;
    float s2 = dx * dx + dy * dy + dz * dz + dw * dw;
    float ws2 = waveReduceSum(s2);
    if (lane == 0) red2[wid] = ws2;
    __syncthreads();
    float var = (red2[0] + red2[1] + red2[2] + red2[3]) * (1.0f / EMB);
    float rs = rsqrtf(var + 1e-5f);
    float4 wv = reinterpret_cast<const float4*>(w)[tid];
    float4 bv = reinterpret_cast<const float4*>(bb)[tid];
    float4 o;
    o.x = dx * rs * wv.x + bv.x;
    o.y = dy * rs * wv.y + bv.y;
    o.z = dz * rs * wv.z + bv.z;
    o.w = dw * rs * wv.w + bv.w;
    reinterpret_cast<float4*>(out)[tid] = o;
}

__global__ __launch_bounds__(256) void ln_kernel(
    const float* __restrict__ x, const float* __restrict__ w,
    const float* __restrict__ b, float* __restrict__ out)
{
    size_t row = blockIdx.x;
    ln_row_256(x + row * EMB, w, b, out + row * EMB);
}

__global__ __launch_bounds__(256) void lnf_last_kernel(
    const float* __restrict__ x, const float* __restrict__ w,
    const float* __restrict__ b, float* __restrict__ xl)
{
    size_t bidx = blockIdx.x;
    ln_row_256(x + (bidx * T_SEQ + (T_SEQ - 1)) * EMB, w, b, xl + bidx * EMB);
}

// ------------- bf16 MFMA GEMM: C[M,N] = A[M,K] @ W[K,N] (+bias, epi) ---
// EPI 0: C = acc + bias
// EPI 1: C = other + acc + bias          (residual)
// EPI 2: C = silu(other) * (acc + bias)  (SiLU-GLU; other = fc1)
// Tile 128x128, BK=32, 256 threads = 4 waves in 2x2; wave tile 64x64 =
// 4x4 fragments of 16x16. A,W are fp32 in HBM; converted to bf16 (RNE)
// during LDS staging. Bs holds W TRANSPOSED ([n][k]) so both fragment
// loads are contiguous ds_read_b128.
// MFMA layouts (cdna4 docs): A: row=lane&15, k=(lane>>4)*8+i;
// B: col=lane&15, k=(lane>>4)*8+i; D: col=lane&15, row=(lane>>4)*4+reg
// (C/D mapping HW-verified, m89/m91).
#define GBM 128
#define GBN 128
#define GBK 32
#define LDT 40   // LDS row stride in bf16 elems (128B per 32-k row + pad)

template <int EPI>
__global__ __launch_bounds__(256) void gemm_bf16_kernel(
    const float* __restrict__ A, const float* __restrict__ W,
    const float* __restrict__ bias, const float* __restrict__ other,
    float* __restrict__ C, int M, int N, int K)
{
    __shared__ unsigned short As[GBM * LDT];   // [row][k]
    __shared__ unsigned short Bs[GBN * LDT];   // [col][k]  (W^T)
    int tid  = threadIdx.x;
    int lane = tid & 63, wid = tid >> 6;
    int wr = wid >> 1, wc = wid & 1;           // 2x2 wave grid
    int row0 = blockIdx.y * GBM, col0 = blockIdx.x * GBN;

    f32x4 acc[4][4] = {};   // acc[m][n]

    const int rbase = wr * 64 + (lane & 15);
    const int cbase = wc * 64 + (lane & 15);
    const int khalf = (lane >> 4) * 8;

    for (int k0 = 0; k0 < K; k0 += GBK) {
        __syncthreads();   // prior iteration's fragment reads done
        // ---- stage A: 128 rows x 32 k (16 elems/thread) ----
        {
            int r = tid >> 1;
            int h = (tid & 1) << 4;
            const float* src = A + (size_t)(row0 + r) * K + k0 + h;
            unsigned short* dst = &As[r * LDT + h];
            float4 f0 = *reinterpret_cast<const float4*>(src + 0);
            float4 f1 = *reinterpret_cast<const float4*>(src + 4);
            float4 f2 = *reinterpret_cast<const float4*>(src + 8);
            float4 f3 = *reinterpret_cast<const float4*>(src + 12);
            dst[0]  = f2bf(f0.x); dst[1]  = f2bf(f0.y); dst[2]  = f2bf(f0.z); dst[3]  = f2bf(f0.w);
            dst[4]  = f2bf(f1.x); dst[5]  = f2bf(f1.y); dst[6]  = f2bf(f1.z); dst[7]  = f2bf(f1.w);
            dst[8]  = f2bf(f2.x); dst[9]  = f2bf(f2.y); dst[10] = f2bf(f2.z); dst[11] = f2bf(f2.w);
            dst[12] = f2bf(f3.x); dst[13] = f2bf(f3.y); dst[14] = f2bf(f3.z); dst[15] = f2bf(f3.w);
        }
        // ---- stage B transposed: W[k0+kr][col0+c] -> Bs[c][kr] ----
        {
            int kr = tid >> 3;
            int c0 = (tid & 7) << 4;
            const float* src = W + (size_t)(k0 + kr) * N + col0 + c0;
#pragma unroll
            for (int j = 0; j < 4; j++) {
                float4 f = *reinterpret_cast<const float4*>(src + 4 * j);
                Bs[(c0 + 4 * j + 0) * LDT + kr] = f2bf(f.x);
                Bs[(c0 + 4 * j + 1) * LDT + kr] = f2bf(f.y);
                Bs[(c0 + 4 * j + 2) * LDT + kr] = f2bf(f.z);
                Bs[(c0 + 4 * j + 3) * LDT + kr] = f2bf(f.w);
            }
        }
        __syncthreads();
        // ---- fragments + MFMA ----
        bf16x8 af[4], bf[4];
#pragma unroll
        for (int m = 0; m < 4; m++)
            af[m] = *reinterpret_cast<const bf16x8*>(&As[(rbase + m * 16) * LDT + khalf]);
#pragma unroll
        for (int n = 0; n < 4; n++)
            bf[n] = *reinterpret_cast<const bf16x8*>(&Bs[(cbase + n * 16) * LDT + khalf]);
#pragma unroll
        for (int m = 0; m < 4; m++)
#pragma unroll
            for (int n = 0; n < 4; n++)
                acc[m][n] = __builtin_amdgcn_mfma_f32_16x16x32_bf16(
                    af[m], bf[n], acc[m][n], 0, 0, 0);
    }

    // ---- epilogue ----
    int rr = (lane >> 4) * 4;
    int cc = lane & 15;
#pragma unroll
    for (int m = 0; m < 4; m++) {
#pragma unroll
        for (int n = 0; n < 4; n++) {
            int gcol = col0 + wc * 64 + n * 16 + cc;
            float bcol = bias[gcol];
#pragma unroll
            for (int r = 0; r < 4; r++) {
                int grow = row0 + wr * 64 + m * 16 + rr + r;
                size_t off = (size_t)grow * N + gcol;
                float v = acc[m][n][r] + bcol;
                if (EPI == 1) v += other[off];
                if (EPI == 2) {
                    float f1 = other[off];
                    v = (f1 / (1.f + __expf(-f1))) * v;
                }
                C[off] = v;
            }
        }
    }
}

// ---------------- qkv split: [B,T,3E] -> q/k/v [B,H,T,D] ----------------
__global__ __launch_bounds__(256) void split_kernel(
    const float* __restrict__ qkv, float* __restrict__ q,
    float* __restrict__ k, float* __restrict__ v)
{
    int i = blockIdx.x * 256 + threadIdx.x;   // over B*T*H*16
    int d4 = i & 15;
    int r  = i >> 4;
    int h  = r & (NHEAD - 1);
    int bt = r >> 4;                           // 0..B*T-1
    int t  = bt & (T_SEQ - 1);
    int b  = bt >> 10;
    size_t src = (size_t)bt * (3 * EMB) + h * HDIM + d4 * 4;
    size_t dst = (((size_t)b * NHEAD + h) * T_SEQ + t) * HDIM + d4 * 4;
    *reinterpret_cast<float4*>(q + dst) = *reinterpret_cast<const float4*>(qkv + src);
    *reinterpret_cast<float4*>(k + dst) = *reinterpret_cast<const float4*>(qkv + src + EMB);
    *reinterpret_cast<float4*>(v + dst) = *reinterpret_cast<const float4*>(qkv + src + 2 * EMB);
}

// ---------------- attention (flash-style, wave per query) ----------------
// Mask (matches reference): (kk<=q && q-kk<=WINDOW) || (kk < spl).
// Prefix term is NOT causal — loop covers max(causal, prefix) chunks.
__global__ __launch_bounds__(1024) void attn_kernel(
    const float* __restrict__ q, const float* __restrict__ k,
    const float* __restrict__ v, const int* __restrict__ spl,
    float* __restrict__ y)
{
    __shared__ float Qs[16][64];
    __shared__ float Ks[64][65];
    __shared__ float Vs[64][65];
    __shared__ float Ps[16][64];

    int q0 = blockIdx.x * 16;
    int h  = blockIdx.y, b = blockIdx.z;
    int tid = threadIdx.x;
    int wid = tid >> 6, lane = tid & 63;
    const size_t bh = ((size_t)b * NHEAD + h) * T_SEQ * HDIM;

    Qs[wid][lane] = q[bh + (size_t)(q0 + wid) * HDIM + lane];

    int s_pl = spl[b];
    int myq = q0 + wid;
    float m_run = -INFINITY, l_run = 0.f, acc = 0.f;
    int kc_top = (q0 + 15) >> 6;                 // causal frontier chunk
    int kc_pref = ((s_pl + 63) >> 6) - 1;        // last prefix chunk
    if (kc_pref > kc_top) kc_top = kc_pref;
    int wlo = q0 - WINDOW;

    for (int kc = 0; kc <= kc_top; ++kc) {
        int k0 = kc << 6;
        bool pref = (k0 < s_pl);
        bool wind = (k0 + 63 >= wlo) && (k0 <= q0 + 15);
        if (!(pref || wind)) continue;          // block-uniform
        __syncthreads();
        {   // stage K,V 64x64 each
            int r = tid >> 4, c4 = tid & 15;
            float4 kk4 = *reinterpret_cast<const float4*>(k + bh + (size_t)(k0 + r) * HDIM + c4 * 4);
            Ks[r][c4 * 4 + 0] = kk4.x; Ks[r][c4 * 4 + 1] = kk4.y;
            Ks[r][c4 * 4 + 2] = kk4.z; Ks[r][c4 * 4 + 3] = kk4.w;
            float4 vv4 = *reinterpret_cast<const float4*>(v + bh + (size_t)(k0 + r) * HDIM + c4 * 4);
            Vs[r][c4 * 4 + 0] = vv4.x; Vs[r][c4 * 4 + 1] = vv4.y;
            Vs[r][c4 * 4 + 2] = vv4.z; Vs[r][c4 * 4 + 3] = vv4.w;
        }
        __syncthreads();

        int kk = k0 + lane;
        bool valid = ((kk <= myq) && (myq - kk) <= WINDOW) || (kk < s_pl);
        float sacc = 0.f;
#pragma unroll
        for (int d = 0; d < 64; d++) sacc = fmaf(Qs[wid][d], Ks[lane][d], sacc);
        sacc *= 0.125f;                              // 1/sqrt(64)
        sacc = 30.0f * tanhf(sacc * (1.0f / 30.0f)); // softcap
        float sv = valid ? sacc : -INFINITY;

        float mc = waveReduceMax(sv);
        float m_new = fmaxf(m_run, mc);
        float alpha = (m_new == -INFINITY) ? 1.0f : expf(m_run - m_new);
        float p = valid ? expf(sv - m_new) : 0.f;
        float lc = waveReduceSum(p);
        l_run = l_run * alpha + lc;
        m_run = m_new;
        Ps[wid][lane] = p;
        __syncthreads();

        acc *= alpha;
#pragma unroll
        for (int j = 0; j < 64; j++) acc = fmaf(Ps[wid][j], Vs[j][lane], acc);
    }
    y[((size_t)b * T_SEQ + myq) * EMB + h * HDIM + lane] = acc / l_run;
}

// ---------------- logits: out[b,v] = dot(xl[b], wte[v]) ----------------
// One block per 4 vocab rows; handles BOTH batches (wte row read once).
__global__ __launch_bounds__(256) void logits_kernel(
    const float* __restrict__ xl, const float* __restrict__ wte,
    float* __restrict__ out)
{
    __shared__ float xs[2][1024];
    int tid = threadIdx.x;
    {
        float4 v0 = *reinterpret_cast<const float4*>(xl + tid * 4);
        float4 v1 = *reinterpret_cast<const float4*>(xl + EMB + tid * 4);
        *reinterpret_cast<float4*>(&xs[0][tid * 4]) = v0;
        *reinterpret_cast<float4*>(&xs[1][tid * 4]) = v1;
    }
    __syncthreads();
    int wid = tid >> 6, lane = tid & 63;
    int vv = blockIdx.x * 4 + wid;
    if (vv < VOCAB) {
        const float* wr = wte + (size_t)vv * EMB;
        float acc0 = 0.f, acc1 = 0.f;
#pragma unroll
        for (int p = 0; p < 4; p++) {
            float4 w4 = *reinterpret_cast<const float4*>(wr + p * 256 + lane * 4);
            int xo = p * 256 + lane * 4;
            acc0 += w4.x * xs[0][xo] + w4.y * xs[0][xo + 1] + w4.z * xs[0][xo + 2] + w4.w * xs[0][xo + 3];
            acc1 += w4.x * xs[1][xo] + w4.y * xs[1][xo + 1] + w4.z * xs[1][xo + 2] + w4.w * xs[1][xo + 3];
        }
        acc0 = waveReduceSum(acc0);
        acc1 = waveReduceSum(acc1);
        if (lane == 0) {
            out[vv] = acc0;
            out[(size_t)VOCAB + vv] = acc1;
        }
    }
}

// ---------------- host launcher ----------------
extern "C" void kernel_launch(void* const* d_in, const int* in_sizes, int n_in,
                              void* d_out, int out_size, void* d_ws, size_t ws_size,
                              hipStream_t stream)
{
    const int*   idx   = (const int*)  d_in[0];
    const int*   spl   = (const int*)  d_in[1];
    const float* wte   = (const float*)d_in[2];
    const float* wpe   = (const float*)d_in[3];
    const float* ln1w  = (const float*)d_in[4];
    const float* ln1b  = (const float*)d_in[5];
    const float* Wqkv  = (const float*)d_in[6];
    const float* bqkv  = (const float*)d_in[7];
    const float* Wo    = (const float*)d_in[8];
    const float* bo    = (const float*)d_in[9];
    const float* ln2w  = (const float*)d_in[10];
    const float* ln2b  = (const float*)d_in[11];
    const float* Wfc   = (const float*)d_in[12];
    const float* bfc   = (const float*)d_in[13];
    const float* Wfc2  = (const float*)d_in[14];
    const float* bfc2  = (const float*)d_in[15];
    const float* Wproj = (const float*)d_in[16];
    const float* bproj = (const float*)d_in[17];
    const float* lnfw  = (const float*)d_in[18];
    const float* lnfb  = (const float*)d_in[19];
    float* out = (float*)d_out;
    float* ws  = (float*)d_ws;

    const size_t NTOK = (size_t)BATCH * T_SEQ;          // 2048
    const size_t XSZ  = NTOK * EMB;                     // 2,097,152 floats
    // Arena: x | hbuf | r1 (qkv -> yb -> fc1) | r2 (q,k,v -> fc2)
    const size_t NEED = (XSZ * 2 + NTOK * 4096 * 2) * sizeof(float); // 83.9 MB
    if (ws_size < NEED) return;  // clean fail (poisoned out) instead of OOB

    float* x    = ws;
    float* hbuf = x + XSZ;
    float* r1   = hbuf + XSZ;
    float* r2   = r1 + NTOK * 4096;

    float* qkvb = r1;
    float* yb   = r1;            // reuses qkv region (dead after split)
    float* fc1  = r1;            // reuses after Wo-GEMM consumed yb
    float* qb   = r2;
    float* kb   = r2 + XSZ;
    float* vb   = r2 + 2 * XSZ;
    float* fc2  = r2;            // reuses q/k/v (dead after attention)
    float* xl   = hbuf;          // hbuf dead by lnf time

    embed_kernel<<<dim3((unsigned)NTOK), 256, 0, stream>>>(idx, wte, wpe, x);

    for (int l = 0; l < NLAYER; ++l) {
        const size_t eoff = (size_t)l * EMB;
        ln_kernel<<<dim3((unsigned)NTOK), 256, 0, stream>>>(x, ln1w + eoff, ln1b + eoff, hbuf);
        gemm_bf16_kernel<0><<<dim3(3072 / GBN, 2048 / GBM), 256, 0, stream>>>(
            hbuf, Wqkv + (size_t)l * EMB * 3 * EMB, bqkv + (size_t)l * 3 * EMB,
            nullptr, qkvb, 2048, 3072, 1024);
        split_kernel<<<dim3((unsigned)(NTOK * NHEAD * 16 / 256)), 256, 0, stream>>>(qkvb, qb, kb, vb);
        attn_kernel<<<dim3(T_SEQ / 16, NHEAD, BATCH), 1024, 0, stream>>>(qb, kb, vb, spl, yb);
        gemm_bf16_kernel<1><<<dim3(1024 / GBN, 2048 / GBM), 256, 0, stream>>>(
            yb, Wo + (size_t)l * EMB * EMB, bo + eoff, x, x, 2048, 1024, 1024);
        ln_kernel<<<dim3((unsigned)NTOK), 256, 0, stream>>>(x, ln2w + eoff, ln2b + eoff, hbuf);
        gemm_bf16_kernel<0><<<dim3(4096 / GBN, 2048 / GBM), 256, 0, stream>>>(
            hbuf, Wfc + (size_t)l * EMB * 4096, bfc + (size_t)l * 4096,
            nullptr, fc1, 2048, 4096, 1024);
        gemm_bf16_kernel<2><<<dim3(4096 / GBN, 2048 / GBM), 256, 0, stream>>>(
            hbuf, Wfc2 + (size_t)l * EMB * 4096, bfc2 + (size_t)l * 4096,
            fc1, fc2, 2048, 4096, 1024);
        gemm_bf16_kernel<1><<<dim3(1024 / GBN, 2048 / GBM), 256, 0, stream>>>(
            fc2, Wproj + (size_t)l * 4096 * EMB, bproj + eoff, x, x, 2048, 1024, 4096);
    }

    lnf_last_kernel<<<dim3(BATCH), 256, 0, stream>>>(x, lnfw, lnfb, xl);
    logits_kernel<<<dim3((VOCAB + 3) / 4), 256, 0, stream>>>(xl, wte, out);
}

// Round 5
// 2583.299 us; speedup vs baseline: 1.7128x; 1.7128x over previous
//
#include <hip/hip_runtime.h>
#include <math.h>

#define T_SEQ   1024
#define BATCH   2
#define EMB     1024
#define NHEAD   16
#define NLAYER  6
#define HDIM    64
#define VOCAB   50257
#define WINDOW  256

typedef unsigned short u16;
typedef short bf16x8 __attribute__((ext_vector_type(8)));
typedef float f32x4  __attribute__((ext_vector_type(4)));

// RNE float -> bf16 bits
__device__ __forceinline__ u16 f2bf(float f) {
    unsigned int u = __float_as_uint(f);
    u += 0x7fffu + ((u >> 16) & 1u);
    return (u16)(u >> 16);
}

// async global->LDS, 16B per lane (LDS dest = wave-uniform base + lane*16)
__device__ __forceinline__ void gload16(const void* g, void* l) {
    __builtin_amdgcn_global_load_lds(
        (const __attribute__((address_space(1))) void*)g,
        (__attribute__((address_space(3))) void*)l, 16, 0, 0);
}

// ---------------- wave reduce helpers ----------------
__device__ __forceinline__ float waveReduceSum(float v) {
#pragma unroll
    for (int o = 32; o > 0; o >>= 1) v += __shfl_xor(v, o, 64);
    return v;
}
__device__ __forceinline__ float waveReduceMax(float v) {
#pragma unroll
    for (int o = 32; o > 0; o >>= 1) v = fmaxf(v, __shfl_xor(v, o, 64));
    return v;
}

// ---------------- embedding ----------------
__global__ __launch_bounds__(256) void embed_kernel(
    const int* __restrict__ idx, const float* __restrict__ wte,
    const float* __restrict__ wpe, float* __restrict__ x)
{
    int i  = blockIdx.x * 256 + threadIdx.x;
    int e4 = i & 255;
    int bt = i >> 8;
    int t  = bt & (T_SEQ - 1);
    int id = idx[bt];
    float4 a = *reinterpret_cast<const float4*>(wte + (size_t)id * EMB + e4 * 4);
    float4 p = *reinterpret_cast<const float4*>(wpe + (size_t)t  * EMB + e4 * 4);
    float4 o; o.x = a.x + p.x; o.y = a.y + p.y; o.z = a.z + p.z; o.w = a.w + p.w;
    *reinterpret_cast<float4*>(x + (size_t)bt * EMB + e4 * 4) = o;
}

// ---------------- LayerNorm core (256 thr, one 1024-row) ----------------
__device__ __forceinline__ float4 ln_row_core(
    const float* __restrict__ in, const float* __restrict__ w,
    const float* __restrict__ bb)
{
    __shared__ float red[4];
    __shared__ float red2[4];
    int tid = threadIdx.x;
    int wid = tid >> 6, lane = tid & 63;
    float4 v = reinterpret_cast<const float4*>(in)[tid];
    float s = v.x + v.y + v.z + v.w;
    float ws = waveReduceSum(s);
    if (lane == 0) red[wid] = ws;
    __syncthreads();
    float mu = (red[0] + red[1] + red[2] + red[3]) * (1.0f / EMB);
    float dx = v.x - mu, dy = v.y - mu, dz = v.z - mu, dw = v.w - mu;
    float s2 = dx * dx + dy * dy + dz * dz + dw * dw;
    float ws2 = waveReduceSum(s2);
    if (lane == 0) red2[wid] = ws2;
    __syncthreads();
    float var = (red2[0] + red2[1] + red2[2] + red2[3]) * (1.0f / EMB);
    float rs = rsqrtf(var + 1e-5f);
    float4 wv = reinterpret_cast<const float4*>(w)[tid];
    float4 bv = reinterpret_cast<const float4*>(bb)[tid];
    float4 o;
    o.x = dx * rs * wv.x + bv.x;
    o.y = dy * rs * wv.y + bv.y;
    o.z = dz * rs * wv.z + bv.z;
    o.w = dw * rs * wv.w + bv.w;
    return o;
}

// LN -> bf16 output (feeds GEMM A)
__global__ __launch_bounds__(256) void ln_bf16_kernel(
    const float* __restrict__ x, const float* __restrict__ w,
    const float* __restrict__ b, u16* __restrict__ out)
{
    size_t row = blockIdx.x;
    float4 o = ln_row_core(x + row * EMB, w, b);
    ushort4 pk;
    pk.x = f2bf(o.x); pk.y = f2bf(o.y); pk.z = f2bf(o.z); pk.w = f2bf(o.w);
    *reinterpret_cast<ushort4*>(out + row * EMB + threadIdx.x * 4) = pk;
}

// lnf on last token of each batch (fp32 out, feeds logits)
__global__ __launch_bounds__(256) void lnf_last_kernel(
    const float* __restrict__ x, const float* __restrict__ w,
    const float* __restrict__ b, float* __restrict__ xl)
{
    size_t bidx = blockIdx.x;
    float4 o = ln_row_core(x + (bidx * T_SEQ + (T_SEQ - 1)) * EMB, w, b);
    reinterpret_cast<float4*>(xl + bidx * EMB)[threadIdx.x] = o;
}

// ---------- weight transpose-convert: W[k][n] fp32 -> Wt[n][k] bf16 ----
// grid (N/64, K/64), 256 threads
__global__ __launch_bounds__(256) void wconv_kernel(
    const float* __restrict__ W, u16* __restrict__ Wt, int K, int N)
{
    __shared__ u16 t[64][72];   // 144B row stride: 16B-aligned slices
    int n0 = blockIdx.x * 64, k0 = blockIdx.y * 64;
    int tid = threadIdx.x;
    int kr = tid >> 4;
    int nc = (tid & 15) * 4;
#pragma unroll
    for (int j = 0; j < 4; j++) {
        int k = kr + j * 16;
        float4 f = *reinterpret_cast<const float4*>(W + (size_t)(k0 + k) * N + n0 + nc);
        t[nc + 0][k] = f2bf(f.x);
        t[nc + 1][k] = f2bf(f.y);
        t[nc + 2][k] = f2bf(f.z);
        t[nc + 3][k] = f2bf(f.w);
    }
    __syncthreads();
    int n = tid >> 2;
    int kc = (tid & 3) * 16;
    u16* dst = Wt + (size_t)(n0 + n) * K + k0 + kc;
    *reinterpret_cast<bf16x8*>(dst)     = *reinterpret_cast<const bf16x8*>(&t[n][kc]);
    *reinterpret_cast<bf16x8*>(dst + 8) = *reinterpret_cast<const bf16x8*>(&t[n][kc + 8]);
}

// ------------- bf16 MFMA GEMM (m97-style): C = A @ Wt^T (+bias, epi) ---
// A [M][K] bf16 row-major; Bt [N][K] bf16 (weight pre-transposed).
// BK=64, 4 waves 2x2, global_load_lds width-16 with XOR-swizzled SOURCE
// (rule #21: linear LDS dest + pre-swizzled global src + same XOR on
// ds_read_b128). LDS row = 64 bf16 = 128B = 8 slots; slot ^= row&7.
// MFMA 16x16x32 layouts (HW-validated round 4): A row=lane&15,
// k=(lane>>4)*8+i; B col=lane&15; D col=lane&15, row=(lane>>4)*4+reg.
// EPI 0: fp32 C = acc + bias
// EPI 1: fp32 C = other + acc + bias          (residual)
// EPI 2: bf16 C = silu(other) * (acc + bias)  (SiLU-GLU)
template <int EPI, int BM, int BN>
__global__ __launch_bounds__(256) void gemm_bf16(
    const u16* __restrict__ A, const u16* __restrict__ Bt,
    const float* __restrict__ bias, const float* __restrict__ other,
    float* __restrict__ Cf, u16* __restrict__ Ch,
    int M, int N, int K)
{
    constexpr int WM = BM / 2, WN = BN / 2;
    constexpr int FM = WM / 16, FN = WN / 16;
    __shared__ u16 As[BM * 64];
    __shared__ u16 Bs[BN * 64];
    int tid = threadIdx.x, lane = tid & 63, wid = tid >> 6;
    int wr = wid >> 1, wc = wid & 1;
    int row0 = blockIdx.y * BM, col0 = blockIdx.x * BN;

    f32x4 acc[FM][FN] = {};

    const int l3 = lane >> 3;          // staging: row within 8-row group
    const int sw = (lane & 7) ^ l3;    // staging: swizzled source slot
    const int lr = lane & 15;
    const int g0 = lane >> 4;
    const int l7 = lane & 7;

    const u16* Ab = A  + (size_t)row0 * K;
    const u16* Bb = Bt + (size_t)col0 * K;

    for (int k0 = 0; k0 < K; k0 += 64) {
        __syncthreads();   // prior iteration's fragment reads complete
        // stage A tile [BM][64]: each instr = 8 rows x 128B
#pragma unroll
        for (int i = 0; i < BM / 32; i++) {
            int m0 = (wid * (BM / 32) + i) * 8;
            gload16(Ab + (size_t)(m0 + l3) * K + k0 + sw * 8, &As[m0 * 64]);
        }
#pragma unroll
        for (int i = 0; i < BN / 32; i++) {
            int n0 = (wid * (BN / 32) + i) * 8;
            gload16(Bb + (size_t)(n0 + l3) * K + k0 + sw * 8, &Bs[n0 * 64]);
        }
        __syncthreads();   // vmcnt(0) drain + barrier: tiles visible
#pragma unroll
        for (int kk = 0; kk < 2; kk++) {
            bf16x8 af[FM], bfr[FN];
            int sl = (kk * 4 + g0) ^ l7;   // un-swizzle on read
#pragma unroll
            for (int m = 0; m < FM; m++) {
                int r = wr * WM + m * 16 + lr;
                af[m] = *reinterpret_cast<const bf16x8*>(&As[r * 64 + sl * 8]);
            }
#pragma unroll
            for (int n = 0; n < FN; n++) {
                int c = wc * WN + n * 16 + lr;
                bfr[n] = *reinterpret_cast<const bf16x8*>(&Bs[c * 64 + sl * 8]);
            }
#pragma unroll
            for (int m = 0; m < FM; m++)
#pragma unroll
                for (int n = 0; n < FN; n++)
                    acc[m][n] = __builtin_amdgcn_mfma_f32_16x16x32_bf16(
                        af[m], bfr[n], acc[m][n], 0, 0, 0);
        }
    }

    // epilogue
#pragma unroll
    for (int m = 0; m < FM; m++) {
#pragma unroll
        for (int n = 0; n < FN; n++) {
            int gcol = col0 + wc * WN + n * 16 + lr;
            float bcol = bias[gcol];
#pragma unroll
            for (int r = 0; r < 4; r++) {
                int grow = row0 + wr * WM + m * 16 + g0 * 4 + r;
                size_t off = (size_t)grow * N + gcol;
                float v = acc[m][n][r] + bcol;
                if (EPI == 1) v += other[off];
                if (EPI == 2) {
                    float f1 = other[off];
                    v = (f1 / (1.f + __expf(-f1))) * v;
                }
                if (EPI == 2) Ch[off] = f2bf(v);
                else          Cf[off] = v;
            }
        }
    }
}

// ---------------- qkv split: [B,T,3E] fp32 -> q/k/v [B,H,T,D] fp32 -----
__global__ __launch_bounds__(256) void split_kernel(
    const float* __restrict__ qkv, float* __restrict__ q,
    float* __restrict__ k, float* __restrict__ v)
{
    int i = blockIdx.x * 256 + threadIdx.x;
    int d4 = i & 15;
    int r  = i >> 4;
    int h  = r & (NHEAD - 1);
    int bt = r >> 4;
    int t  = bt & (T_SEQ - 1);
    int b  = bt >> 10;
    size_t src = (size_t)bt * (3 * EMB) + h * HDIM + d4 * 4;
    size_t dst = (((size_t)b * NHEAD + h) * T_SEQ + t) * HDIM + d4 * 4;
    *reinterpret_cast<float4*>(q + dst) = *reinterpret_cast<const float4*>(qkv + src);
    *reinterpret_cast<float4*>(k + dst) = *reinterpret_cast<const float4*>(qkv + src + EMB);
    *reinterpret_cast<float4*>(v + dst) = *reinterpret_cast<const float4*>(qkv + src + 2 * EMB);
}

// ---------------- attention (flash-style, wave per query) ----------------
// Mask (matches reference): (kk<=q && q-kk<=WINDOW) || (kk < spl).
// Prefix term is NOT causal. Output written as bf16 (feeds Wo GEMM).
__global__ __launch_bounds__(1024) void attn_kernel(
    const float* __restrict__ q, const float* __restrict__ k,
    const float* __restrict__ v, const int* __restrict__ spl,
    u16* __restrict__ y)
{
    __shared__ float Qs[16][64];
    __shared__ float Ks[64][65];
    __shared__ float Vs[64][65];
    __shared__ float Ps[16][64];

    int q0 = blockIdx.x * 16;
    int h  = blockIdx.y, b = blockIdx.z;
    int tid = threadIdx.x;
    int wid = tid >> 6, lane = tid & 63;
    const size_t bh = ((size_t)b * NHEAD + h) * T_SEQ * HDIM;

    Qs[wid][lane] = q[bh + (size_t)(q0 + wid) * HDIM + lane];

    int s_pl = spl[b];
    int myq = q0 + wid;
    float m_run = -INFINITY, l_run = 0.f, acc = 0.f;
    int kc_top = (q0 + 15) >> 6;
    int kc_pref = ((s_pl + 63) >> 6) - 1;
    if (kc_pref > kc_top) kc_top = kc_pref;
    int wlo = q0 - WINDOW;

    for (int kc = 0; kc <= kc_top; ++kc) {
        int k0 = kc << 6;
        bool pref = (k0 < s_pl);
        bool wind = (k0 + 63 >= wlo) && (k0 <= q0 + 15);
        if (!(pref || wind)) continue;          // block-uniform
        __syncthreads();
        {
            int r = tid >> 4, c4 = tid & 15;
            float4 kk4 = *reinterpret_cast<const float4*>(k + bh + (size_t)(k0 + r) * HDIM + c4 * 4);
            Ks[r][c4 * 4 + 0] = kk4.x; Ks[r][c4 * 4 + 1] = kk4.y;
            Ks[r][c4 * 4 + 2] = kk4.z; Ks[r][c4 * 4 + 3] = kk4.w;
            float4 vv4 = *reinterpret_cast<const float4*>(v + bh + (size_t)(k0 + r) * HDIM + c4 * 4);
            Vs[r][c4 * 4 + 0] = vv4.x; Vs[r][c4 * 4 + 1] = vv4.y;
            Vs[r][c4 * 4 + 2] = vv4.z; Vs[r][c4 * 4 + 3] = vv4.w;
        }
        __syncthreads();

        int kk = k0 + lane;
        bool valid = ((kk <= myq) && (myq - kk) <= WINDOW) || (kk < s_pl);
        float sacc = 0.f;
#pragma unroll
        for (int d = 0; d < 64; d++) sacc = fmaf(Qs[wid][d], Ks[lane][d], sacc);
        sacc *= 0.125f;
        sacc = 30.0f * tanhf(sacc * (1.0f / 30.0f));
        float sv = valid ? sacc : -INFINITY;

        float mc = waveReduceMax(sv);
        float m_new = fmaxf(m_run, mc);
        float alpha = (m_new == -INFINITY) ? 1.0f : expf(m_run - m_new);
        float p = valid ? expf(sv - m_new) : 0.f;
        float lc = waveReduceSum(p);
        l_run = l_run * alpha + lc;
        m_run = m_new;
        Ps[wid][lane] = p;
        __syncthreads();

        acc *= alpha;
#pragma unroll
        for (int j = 0; j < 64; j++) acc = fmaf(Ps[wid][j], Vs[j][lane], acc);
    }
    y[((size_t)b * T_SEQ + myq) * EMB + h * HDIM + lane] = f2bf(acc / l_run);
}

// ---------------- logits: out[b,v] = dot(xl[b], wte[v]) ----------------
__global__ __launch_bounds__(256) void logits_kernel(
    const float* __restrict__ xl, const float* __restrict__ wte,
    float* __restrict__ out)
{
    __shared__ float xs[2][1024];
    int tid = threadIdx.x;
    {
        float4 v0 = *reinterpret_cast<const float4*>(xl + tid * 4);
        float4 v1 = *reinterpret_cast<const float4*>(xl + EMB + tid * 4);
        *reinterpret_cast<float4*>(&xs[0][tid * 4]) = v0;
        *reinterpret_cast<float4*>(&xs[1][tid * 4]) = v1;
    }
    __syncthreads();
    int wid = tid >> 6, lane = tid & 63;
    int vv = blockIdx.x * 4 + wid;
    if (vv < VOCAB) {
        const float* wr = wte + (size_t)vv * EMB;
        float acc0 = 0.f, acc1 = 0.f;
#pragma unroll
        for (int p = 0; p < 4; p++) {
            float4 w4 = *reinterpret_cast<const float4*>(wr + p * 256 + lane * 4);
            int xo = p * 256 + lane * 4;
            acc0 += w4.x * xs[0][xo] + w4.y * xs[0][xo + 1] + w4.z * xs[0][xo + 2] + w4.w * xs[0][xo + 3];
            acc1 += w4.x * xs[1][xo] + w4.y * xs[1][xo + 1] + w4.z * xs[1][xo + 2] + w4.w * xs[1][xo + 3];
        }
        acc0 = waveReduceSum(acc0);
        acc1 = waveReduceSum(acc1);
        if (lane == 0) {
            out[vv] = acc0;
            out[(size_t)VOCAB + vv] = acc1;
        }
    }
}

// ---------------- host launcher ----------------
extern "C" void kernel_launch(void* const* d_in, const int* in_sizes, int n_in,
                              void* d_out, int out_size, void* d_ws, size_t ws_size,
                              hipStream_t stream)
{
    const int*   idx   = (const int*)  d_in[0];
    const int*   spl   = (const int*)  d_in[1];
    const float* wte   = (const float*)d_in[2];
    const float* wpe   = (const float*)d_in[3];
    const float* ln1w  = (const float*)d_in[4];
    const float* ln1b  = (const float*)d_in[5];
    const float* Wqkv  = (const float*)d_in[6];
    const float* bqkv  = (const float*)d_in[7];
    const float* Wo    = (const float*)d_in[8];
    const float* bo    = (const float*)d_in[9];
    const float* ln2w  = (const float*)d_in[10];
    const float* ln2b  = (const float*)d_in[11];
    const float* Wfc   = (const float*)d_in[12];
    const float* bfc   = (const float*)d_in[13];
    const float* Wfc2  = (const float*)d_in[14];
    const float* bfc2  = (const float*)d_in[15];
    const float* Wproj = (const float*)d_in[16];
    const float* bproj = (const float*)d_in[17];
    const float* lnfw  = (const float*)d_in[18];
    const float* lnfb  = (const float*)d_in[19];
    float* out = (float*)d_out;
    float* ws  = (float*)d_ws;

    const size_t NTOK = (size_t)BATCH * T_SEQ;          // 2048
    const size_t XSZ  = NTOK * EMB;                     // 2,097,152
    // Arena (floats): x | hbuf(bf16) | r1 | r2 | yb(bf16) | wT(bf16)
    const size_t NEED = 10 * XSZ * sizeof(float);       // 83.9 MB (proven fit)
    if (ws_size < NEED) return;                         // clean fail, not OOB

    float* x    = ws;
    float* hbuf = x + XSZ;                  // XSZ/2 floats (bf16 LN out)
    float* r1   = hbuf + XSZ / 2;           // 4*XSZ: qkv fp32 | fc1 fp32 | xl
    float* r2   = r1 + 4 * XSZ;             // 3*XSZ: q,k,v fp32 | glu bf16
    float* yb   = r2 + 3 * XSZ;             // XSZ/2 floats (bf16 attn out)
    float* wT   = yb + XSZ / 2;             // XSZ floats = 2*XSZ bf16 (max 4096x1024)

    u16* hbufW = (u16*)hbuf;
    u16* ybW   = (u16*)yb;
    u16* wTW   = (u16*)wT;
    u16* gluW  = (u16*)r2;
    float* qkvb = r1;
    float* fc1  = r1;
    float* qb   = r2;
    float* kb   = r2 + XSZ;
    float* vb   = r2 + 2 * XSZ;
    float* xl   = r1;                       // fc1 dead by lnf time

    embed_kernel<<<dim3((unsigned)NTOK), 256, 0, stream>>>(idx, wte, wpe, x);

    for (int l = 0; l < NLAYER; ++l) {
        const size_t eoff = (size_t)l * EMB;
        // ---- attention block ----
        ln_bf16_kernel<<<dim3((unsigned)NTOK), 256, 0, stream>>>(x, ln1w + eoff, ln1b + eoff, hbufW);
        wconv_kernel<<<dim3(3072 / 64, 1024 / 64), 256, 0, stream>>>(
            Wqkv + (size_t)l * EMB * 3 * EMB, wTW, 1024, 3072);
        gemm_bf16<0, 128, 128><<<dim3(3072 / 128, 2048 / 128), 256, 0, stream>>>(
            hbufW, wTW, bqkv + (size_t)l * 3 * EMB, nullptr, qkvb, nullptr, 2048, 3072, 1024);
        split_kernel<<<dim3((unsigned)(NTOK * NHEAD * 16 / 256)), 256, 0, stream>>>(qkvb, qb, kb, vb);
        attn_kernel<<<dim3(T_SEQ / 16, NHEAD, BATCH), 1024, 0, stream>>>(qb, kb, vb, spl, ybW);
        wconv_kernel<<<dim3(1024 / 64, 1024 / 64), 256, 0, stream>>>(
            Wo + (size_t)l * EMB * EMB, wTW, 1024, 1024);
        gemm_bf16<1, 64, 64><<<dim3(1024 / 64, 2048 / 64), 256, 0, stream>>>(
            ybW, wTW, bo + eoff, x, x, nullptr, 2048, 1024, 1024);
        // ---- MLP block ----
        ln_bf16_kernel<<<dim3((unsigned)NTOK), 256, 0, stream>>>(x, ln2w + eoff, ln2b + eoff, hbufW);
        wconv_kernel<<<dim3(4096 / 64, 1024 / 64), 256, 0, stream>>>(
            Wfc + (size_t)l * EMB * 4096, wTW, 1024, 4096);
        gemm_bf16<0, 128, 128><<<dim3(4096 / 128, 2048 / 128), 256, 0, stream>>>(
            hbufW, wTW, bfc + (size_t)l * 4096, nullptr, fc1, nullptr, 2048, 4096, 1024);
        wconv_kernel<<<dim3(4096 / 64, 1024 / 64), 256, 0, stream>>>(
            Wfc2 + (size_t)l * EMB * 4096, wTW, 1024, 4096);
        gemm_bf16<2, 128, 128><<<dim3(4096 / 128, 2048 / 128), 256, 0, stream>>>(
            hbufW, wTW, bfc2 + (size_t)l * 4096, fc1, nullptr, gluW, 2048, 4096, 1024);
        wconv_kernel<<<dim3(1024 / 64, 4096 / 64), 256, 0, stream>>>(
            Wproj + (size_t)l * 4096 * EMB, wTW, 4096, 1024);
        gemm_bf16<1, 64, 64><<<dim3(1024 / 64, 2048 / 64), 256, 0, stream>>>(
            gluW, wTW, bproj + eoff, x, x, nullptr, 2048, 1024, 4096);
    }

    lnf_last_kernel<<<dim3(BATCH), 256, 0, stream>>>(x, lnfw, lnfb, xl);
    logits_kernel<<<dim3((VOCAB + 3) / 4), 256, 0, stream>>>(xl, wte, out);
}